// Round 5
// baseline (456.302 us; speedup 1.0000x reference)
//
#include <hip/hip_runtime.h>
#include <hip/hip_bf16.h>

// Problem: B=32, T=256, I=128, H=128, C=100. All fp32.
// out = (h_T + attn_c_final) @ w_fc.T + b_fc; only the LAST step's attention
// matters (scan carry overwrites attn_c each step).

#define Bsz 32
#define Tsz 256
#define Isz 128
#define Hsz 128
#define Csz 100
#define G4H 512   // 4*H

// ---------------- device helpers ----------------
__device__ __forceinline__ float2 pk_fma(float2 a, float2 b, float2 c) {
    float2 d;
    asm("v_pk_fma_f32 %0, %1, %2, %3" : "=v"(d) : "v"(a), "v"(b), "v"(c));
    return d;
}
// sum across the 4 lanes of a quad via DPP quad_perm (VALU pipe, no LDS)
__device__ __forceinline__ float quad_rsum(float x) {
    int t = __builtin_amdgcn_update_dpp(0, __float_as_int(x), 0xB1, 0xF, 0xF, true); // xor 1
    x += __int_as_float(t);
    t = __builtin_amdgcn_update_dpp(0, __float_as_int(x), 0x4E, 0xF, 0xF, true);     // xor 2
    x += __int_as_float(t);
    return x;
}
__device__ __forceinline__ float rcpf(float x) { return __builtin_amdgcn_rcpf(x); }
__device__ __forceinline__ float sigm_n(float x) { return rcpf(1.0f + __expf(-x)); }
__device__ __forceinline__ float tanh_n(float x) {
    float ax = fabsf(x);
    float e = __expf(-2.0f * ax);
    float t = (1.0f - e) * rcpf(1.0f + e);
    return copysignf(t, x);
}
__device__ __forceinline__ float tanh_s(float x) { return tanh_n(x); }

// ---------------- kernel 0: prep ----------------
// wih_t: (K=128, 512) for gemm1. bias = b_ih + b_hh.
// whh_pk: packed for lstm_seq pk_fma; dest idx bit fields:
//   [1:0]=j4, [3:2]=q, [10:4]=d, [12:11]=gi, [15:13]=kk4
//   source k = q*32 + kk4*4 + j4, source row j = gi*128 + d  (w_hh is (4H,H))
__global__ __launch_bounds__(256) void prep_kernel(
    const float* __restrict__ w_ih, const float* __restrict__ b_ih,
    const float* __restrict__ w_hh, const float* __restrict__ b_hh,
    float* __restrict__ wih_t, float* __restrict__ whh_pk, float* __restrict__ bias) {
    int idx = blockIdx.x * blockDim.x + threadIdx.x;   // 0..65535
    if (idx < G4H * Isz) {
        int j = idx >> 7;
        int k = idx & 127;
        wih_t[k * G4H + j] = w_ih[idx];

        int j4  = idx & 3;
        int q   = (idx >> 2) & 3;
        int d   = (idx >> 4) & 127;
        int gi  = (idx >> 11) & 3;
        int kk4 = (idx >> 13) & 7;
        whh_pk[idx] = w_hh[(size_t)((gi << 7) + d) * 128 + (q << 5) + (kk4 << 2) + j4];
    }
    if (idx < G4H) bias[idx] = b_ih[idx] + b_hh[idx];
}

// ---------------- gemm128: C[M,N] = A[M,K] @ B[K,N] (+bias[N]) ----------------
#define GBK 16
#define GLD 132

__global__ __launch_bounds__(256) void gemm128(
    const float* __restrict__ A, const float* __restrict__ Bm,
    const float* __restrict__ bias, float* __restrict__ C,
    int M, int N, int K) {
    __shared__ float As[GBK][GLD];
    __shared__ float Bs[GBK][GLD];
    const int tid = threadIdx.x;
    const int bm = blockIdx.y * 128;
    const int bn = blockIdx.x * 128;
    const int tx = tid & 15, ty = tid >> 4;
    float acc[8][8] = {};

    const int ar = tid >> 2;
    const int ac = (tid & 3) * 4;
    const int br = tid >> 5;
    const int bc = (tid & 31) * 4;

    for (int k0 = 0; k0 < K; k0 += GBK) {
        #pragma unroll
        for (int h = 0; h < 2; ++h) {
            int r = ar + 64 * h;
            float4 v = *(const float4*)(A + (size_t)(bm + r) * K + k0 + ac);
            As[ac + 0][r] = v.x;
            As[ac + 1][r] = v.y;
            As[ac + 2][r] = v.z;
            As[ac + 3][r] = v.w;
        }
        #pragma unroll
        for (int h = 0; h < 2; ++h) {
            int kr = br + 8 * h;
            float4 v = *(const float4*)(Bm + (size_t)(k0 + kr) * N + bn + bc);
            *(float4*)&Bs[kr][bc] = v;
        }
        __syncthreads();
        #pragma unroll
        for (int kk = 0; kk < GBK; ++kk) {
            float a[8], b[8];
            *(float4*)&a[0] = *(const float4*)&As[kk][ty * 8];
            *(float4*)&a[4] = *(const float4*)&As[kk][ty * 8 + 4];
            *(float4*)&b[0] = *(const float4*)&Bs[kk][tx * 8];
            *(float4*)&b[4] = *(const float4*)&Bs[kk][tx * 8 + 4];
            #pragma unroll
            for (int i = 0; i < 8; ++i)
                #pragma unroll
                for (int j = 0; j < 8; ++j)
                    acc[i][j] = fmaf(a[i], b[j], acc[i][j]);
        }
        __syncthreads();
    }
    float bb[8];
    #pragma unroll
    for (int j = 0; j < 8; ++j) bb[j] = bias ? bias[bn + tx * 8 + j] : 0.0f;
    #pragma unroll
    for (int i = 0; i < 8; ++i) {
        int row = bm + ty * 8 + i;
        float4 v0, v1;
        v0.x = acc[i][0] + bb[0]; v0.y = acc[i][1] + bb[1];
        v0.z = acc[i][2] + bb[2]; v0.w = acc[i][3] + bb[3];
        v1.x = acc[i][4] + bb[4]; v1.y = acc[i][5] + bb[5];
        v1.z = acc[i][6] + bb[6]; v1.w = acc[i][7] + bb[7];
        *(float4*)(C + (size_t)row * N + bn + tx * 8) = v0;
        *(float4*)(C + (size_t)row * N + bn + tx * 8 + 4) = v1;
    }
}

// ---------------- gemm_tn (64-tile, for the small KV gemm) ----------------
#define BM 64
#define BN 64
#define BKt 64
#define LDP 68

__global__ __launch_bounds__(256) void gemm_tn(
    const float* __restrict__ A, const float* __restrict__ Bm,
    const float* __restrict__ bias, float* __restrict__ C,
    int M, int N, int K) {
    __shared__ float As[BKt][LDP];
    __shared__ float Bs[BKt][LDP];
    int tid = threadIdx.x;
    int bm = blockIdx.y * BM;
    int bn = blockIdx.x * BN;
    int tx = tid & 15, ty = tid >> 4;
    float acc[4][4] = {};

    int lr = tid >> 4;
    int lc = (tid & 15) * 4;

    for (int k0 = 0; k0 < K; k0 += BKt) {
        #pragma unroll
        for (int p = 0; p < 4; ++p) {
            int row = p * 16 + lr;
            float4 v = *(const float4*)(A + (size_t)(bm + row) * K + k0 + lc);
            As[lc + 0][row] = v.x;
            As[lc + 1][row] = v.y;
            As[lc + 2][row] = v.z;
            As[lc + 3][row] = v.w;
        }
        #pragma unroll
        for (int p = 0; p < 4; ++p) {
            int kr = p * 16 + lr;
            float4 v = *(const float4*)(Bm + (size_t)(k0 + kr) * N + bn + lc);
            *(float4*)&Bs[kr][lc] = v;
        }
        __syncthreads();
        #pragma unroll
        for (int kk = 0; kk < BKt; ++kk) {
            float4 a = *(const float4*)&As[kk][ty * 4];
            float4 b = *(const float4*)&Bs[kk][tx * 4];
            acc[0][0] = fmaf(a.x, b.x, acc[0][0]);
            acc[0][1] = fmaf(a.x, b.y, acc[0][1]);
            acc[0][2] = fmaf(a.x, b.z, acc[0][2]);
            acc[0][3] = fmaf(a.x, b.w, acc[0][3]);
            acc[1][0] = fmaf(a.y, b.x, acc[1][0]);
            acc[1][1] = fmaf(a.y, b.y, acc[1][1]);
            acc[1][2] = fmaf(a.y, b.z, acc[1][2]);
            acc[1][3] = fmaf(a.y, b.w, acc[1][3]);
            acc[2][0] = fmaf(a.z, b.x, acc[2][0]);
            acc[2][1] = fmaf(a.z, b.y, acc[2][1]);
            acc[2][2] = fmaf(a.z, b.z, acc[2][2]);
            acc[2][3] = fmaf(a.z, b.w, acc[2][3]);
            acc[3][0] = fmaf(a.w, b.x, acc[3][0]);
            acc[3][1] = fmaf(a.w, b.y, acc[3][1]);
            acc[3][2] = fmaf(a.w, b.z, acc[3][2]);
            acc[3][3] = fmaf(a.w, b.w, acc[3][3]);
        }
        __syncthreads();
    }
    float bb[4] = {0.f, 0.f, 0.f, 0.f};
    if (bias) {
        bb[0] = bias[bn + tx * 4 + 0];
        bb[1] = bias[bn + tx * 4 + 1];
        bb[2] = bias[bn + tx * 4 + 2];
        bb[3] = bias[bn + tx * 4 + 3];
    }
    #pragma unroll
    for (int i = 0; i < 4; ++i) {
        int row = bm + ty * 4 + i;
        float4 v;
        v.x = acc[i][0] + bb[0];
        v.y = acc[i][1] + bb[1];
        v.z = acc[i][2] + bb[2];
        v.w = acc[i][3] + bb[3];
        *(float4*)(C + (size_t)row * N + bn + tx * 4) = v;
    }
}

// ---------------- kernel 2: wave-specialized sequential LSTM ----------------
// 640 threads = 10 waves. Waves 0..7 (512 thr): compute — NO global memory ops
// in the step loop, so their per-barrier s_waitcnt drains only LDS counters.
// Wave 8: G loader — copies the next 8-step G chunk (16 KB) into a
// double-buffered LDS ring. Wave 9: H storer — writes the previous 8-step
// h chunk from LDS to H_all. Global-latency drains are paid only in the IO
// waves' own barrier joins (s_waitcnt is per-wave state), with 8 steps of slack.
#define HPAD(k) ((k) + 8 * ((k) >> 5))
#define LSTMT 640

__global__ __launch_bounds__(LSTMT, 1) void lstm_seq(
    const float* __restrict__ G, const float* __restrict__ whh_pk,
    float* __restrict__ H_all) {
    const int b = blockIdx.x;
    const int tid = threadIdx.x;
    const int wav = tid >> 6;          // 0..9
    const int lane = tid & 63;
    const int d = tid >> 2;            // compute role (tid<512): 0..127
    const int q = tid & 3;

    __shared__ float h_s[2][160];
    __shared__ float gring[2][8][G4H]; // 32 KB: G chunks, double-buffered
    __shared__ float ring[2][8][Hsz];  // 8 KB: h chunks, double-buffered

    const float* Gb = G + (size_t)b * Tsz * G4H;
    float* Hb = H_all + (size_t)b * Tsz * Hsz;

    // compute waves: weights into 128 VGPRs (one-time)
    float2 w2v[4][16];
    if (wav < 8) {
        const float4* wp = (const float4*)whh_pk;
        #pragma unroll
        for (int kk4 = 0; kk4 < 8; ++kk4)
            #pragma unroll
            for (int gi = 0; gi < 4; ++gi) {
                float4 v = wp[((kk4 * 4 + gi) * 128 + d) * 4 + q];
                w2v[gi][kk4 * 2]     = make_float2(v.x, v.y);
                w2v[gi][kk4 * 2 + 1] = make_float2(v.z, v.w);
            }
    }

    // prologue: chunk 0 of G into gring[0] (all threads), h_s zero
    for (int i4 = tid; i4 < 1024; i4 += LSTMT)
        ((float4*)&gring[0][0][0])[i4] = ((const float4*)Gb)[i4];
    if (tid < 320) ((float*)h_s)[tid] = 0.0f;
    float c = 0.0f;
    __syncthreads();

    int cur = 0;
    for (int t = 0; t < Tsz; ++t) {
        const int chunk = t >> 3;
        const int ph = t & 7;
        const int par = chunk & 1;

        if (wav < 8) {
            // ---- compute step (pure LDS + VALU) ----
            float gval = gring[par][ph][q * 128 + d];
            float2 accA[4], accB[4];
            #pragma unroll
            for (int gi = 0; gi < 4; ++gi) {
                accA[gi] = make_float2(q == gi ? gval : 0.f, 0.f);
                accB[gi] = make_float2(0.f, 0.f);
            }
            const float4* hb4 = (const float4*)&h_s[cur][q * 40];
            #pragma unroll
            for (int kk4 = 0; kk4 < 8; ++kk4) {
                float4 h4 = hb4[kk4];
                float2 hA = make_float2(h4.x, h4.y);
                float2 hB = make_float2(h4.z, h4.w);
                accA[0] = pk_fma(hA, w2v[0][2 * kk4], accA[0]);
                accA[1] = pk_fma(hA, w2v[1][2 * kk4], accA[1]);
                accA[2] = pk_fma(hA, w2v[2][2 * kk4], accA[2]);
                accA[3] = pk_fma(hA, w2v[3][2 * kk4], accA[3]);
                accB[0] = pk_fma(hB, w2v[0][2 * kk4 + 1], accB[0]);
                accB[1] = pk_fma(hB, w2v[1][2 * kk4 + 1], accB[1]);
                accB[2] = pk_fma(hB, w2v[2][2 * kk4 + 1], accB[2]);
                accB[3] = pk_fma(hB, w2v[3][2 * kk4 + 1], accB[3]);
            }
            float a0 = quad_rsum(accA[0].x + accA[0].y + accB[0].x + accB[0].y);
            float a1 = quad_rsum(accA[1].x + accA[1].y + accB[1].x + accB[1].y);
            float a2 = quad_rsum(accA[2].x + accA[2].y + accB[2].x + accB[2].y);
            float a3 = quad_rsum(accA[3].x + accA[3].y + accB[3].x + accB[3].y);

            float iv = sigm_n(a0);
            float fv = sigm_n(a1);
            float gv = tanh_n(a2);
            float ov = sigm_n(a3);
            c = fv * c + iv * gv;
            float h = ov * tanh_n(c);

            if (q == 0) {
                h_s[cur ^ 1][HPAD(d)] = h;
                ring[par][ph][d] = h;
            }
            cur ^= 1;
        } else if (wav == 8) {
            // ---- G loader: fetch chunk+1 into gring[(chunk+1)&1] ----
            if (ph == 4 && chunk < 31) {
                const float4* src = (const float4*)(Gb + (size_t)(chunk + 1) * 4096);
                float4* dst = (float4*)&gring[(chunk + 1) & 1][0][0];
                float4 tmp[16];
                #pragma unroll
                for (int s = 0; s < 16; ++s) tmp[s] = src[lane + 64 * s];
                #pragma unroll
                for (int s = 0; s < 16; ++s) dst[lane + 64 * s] = tmp[s];
            }
        } else {
            // ---- H storer: write chunk-1 from ring to H_all ----
            if (ph == 0 && chunk > 0) {
                const float4* rs = (const float4*)&ring[(chunk - 1) & 1][0][0];
                float4* dsg = (float4*)(Hb + (size_t)(chunk - 1) * 1024);
                float4 tmp[4];
                #pragma unroll
                for (int s = 0; s < 4; ++s) tmp[s] = rs[lane + 64 * s];
                #pragma unroll
                for (int s = 0; s < 4; ++s) dsg[lane + 64 * s] = tmp[s];
            }
        }
        __syncthreads();
    }

    // epilogue: final chunk (31, parity 1) -> H_all rows 248..255
    if (wav == 9) {
        const float4* rs = (const float4*)&ring[1][0][0];
        float4* dsg = (float4*)(Hb + (size_t)31 * 1024);
        #pragma unroll
        for (int s = 0; s < 4; ++s) dsg[lane + 64 * s] = rs[lane + 64 * s];
    }
}

// ---------------- kernel 3: final attention + FC, one WG per batch ----------------
__global__ __launch_bounds__(256) void attn_out(
    const float* __restrict__ H_all, const float* __restrict__ KV,
    const float* __restrict__ w1, const float* __restrict__ w2,
    const float* __restrict__ w_fc, const float* __restrict__ b_fc,
    float* __restrict__ out) {
    int b = blockIdx.x;
    int tid = threadIdx.x;
    __shared__ float hT[Hsz];
    __shared__ float q_s[Hsz];
    __shared__ float w2s[Hsz];
    __shared__ float s_s[Tsz];
    __shared__ float r2[2][Hsz];
    __shared__ float r_s[Hsz];

    const float* Hb = H_all + (size_t)b * Tsz * Hsz;
    const float* KVb = KV + (size_t)b * Tsz * Hsz;

    if (tid < Hsz) {
        hT[tid] = Hb[255 * Hsz + tid];
        w2s[tid] = w2[tid];
    }
    __syncthreads();
    if (tid < Hsz) {
        float acc = 0.f;
        #pragma unroll 8
        for (int k = 0; k < Hsz; ++k) acc = fmaf(hT[k], w1[k * Hsz + tid], acc);
        q_s[tid] = acc;
    }
    __syncthreads();

    const int qd = tid >> 2, ql = tid & 3;
    #pragma unroll
    for (int jj = 0; jj < 4; ++jj) {
        int j = qd + jj * 64;
        float p = 0.f;
        if (j < 255) {
            const float* kv = KVb + (size_t)j * Hsz + ql * 32;
            const float* qs = q_s + ql * 32;
            const float* wv = w2s + ql * 32;
            #pragma unroll 8
            for (int k = 0; k < 32; ++k)
                p = fmaf(tanh_s(qs[k] + kv[k]), wv[k], p);
        }
        p = quad_rsum(p);
        if (ql == 0 && j < 255) s_s[j] = p;
    }
    __syncthreads();

    {
        int dd = tid & 127, half = tid >> 7;
        int j0 = half * 128, je = half ? 255 : 128;
        float acc = 0.f;
        #pragma unroll 4
        for (int j = j0; j < je; ++j) acc = fmaf(s_s[j], Hb[(size_t)j * Hsz + dd], acc);
        r2[half][dd] = acc;
    }
    __syncthreads();
    if (tid < Hsz) r_s[tid] = hT[tid] + r2[0][tid] + r2[1][tid];
    __syncthreads();

    {
        int o = tid >> 1, half = tid & 1;
        float acc = 0.f;
        if (o < Csz) {
            const float* wr = w_fc + (size_t)o * Hsz + half * 64;
            const float* rr = r_s + half * 64;
            #pragma unroll 8
            for (int k = 0; k < 64; ++k) acc = fmaf(rr[k], wr[k], acc);
        }
        acc += __shfl_xor(acc, 1);
        if (half == 0 && o < Csz) out[b * Csz + o] = acc + b_fc[o];
    }
}

// ---------------- launch ----------------
extern "C" void kernel_launch(void* const* d_in, const int* in_sizes, int n_in,
                              void* d_out, int out_size, void* d_ws, size_t ws_size,
                              hipStream_t stream) {
    const float* x    = (const float*)d_in[0];
    const float* w_ih = (const float*)d_in[1];
    const float* b_ih = (const float*)d_in[2];
    const float* w_hh = (const float*)d_in[3];
    const float* b_hh = (const float*)d_in[4];
    const float* w1   = (const float*)d_in[5];
    const float* w2   = (const float*)d_in[6];
    const float* w_fc = (const float*)d_in[7];
    const float* b_fc = (const float*)d_in[8];

    float* ws = (float*)d_ws;
    float* wih_t  = ws;                      // 128*512
    float* whh_pk = wih_t + 65536;           // 128*512 (packed lstm layout)
    float* bias   = whh_pk + 65536;          // 512
    float* G      = bias + 512;              // 8192*512
    float* H_all  = G + 4194304;             // 32*256*128
    float* KV     = H_all + 1048576;         // 32*256*128

    prep_kernel<<<256, 256, 0, stream>>>(w_ih, b_ih, w_hh, b_hh, wih_t, whh_pk, bias);

    dim3 g1(G4H / 128, (Bsz * Tsz) / 128);   // (4, 64)
    gemm128<<<g1, 256, 0, stream>>>(x, wih_t, bias, G, Bsz * Tsz, G4H, Isz);

    lstm_seq<<<Bsz, LSTMT, 0, stream>>>(G, whh_pk, H_all);

    dim3 g2(Hsz / BN, (Bsz * Tsz) / BM);     // (2, 128)
    gemm_tn<<<g2, 256, 0, stream>>>(H_all, w1 + Hsz * Hsz, nullptr, KV, Bsz * Tsz, Hsz, Hsz);

    attn_out<<<Bsz, 256, 0, stream>>>(H_all, KV, w1, w2, w_fc, b_fc, (float*)d_out);
}

// Round 6
// 341.071 us; speedup vs baseline: 1.3379x; 1.3379x over previous
//
#include <hip/hip_runtime.h>
#include <hip/hip_bf16.h>

// Problem: B=32, T=256, I=128, H=128, C=100. All fp32.
// out = (h_T + attn_c_final) @ w_fc.T + b_fc; only the LAST step's attention
// matters (scan carry overwrites attn_c each step).

#define Bsz 32
#define Tsz 256
#define Isz 128
#define Hsz 128
#define Csz 100
#define G4H 512   // 4*H

// ---------------- device helpers ----------------
__device__ __forceinline__ float2 pk_fma(float2 a, float2 b, float2 c) {
    float2 d;
    asm("v_pk_fma_f32 %0, %1, %2, %3" : "=v"(d) : "v"(a), "v"(b), "v"(c));
    return d;
}
// sum across the 4 lanes of a quad via DPP quad_perm (VALU pipe, no LDS)
__device__ __forceinline__ float quad_rsum(float x) {
    int t = __builtin_amdgcn_update_dpp(0, __float_as_int(x), 0xB1, 0xF, 0xF, true); // xor 1
    x += __int_as_float(t);
    t = __builtin_amdgcn_update_dpp(0, __float_as_int(x), 0x4E, 0xF, 0xF, true);     // xor 2
    x += __int_as_float(t);
    return x;
}
__device__ __forceinline__ float rcpf(float x) { return __builtin_amdgcn_rcpf(x); }
__device__ __forceinline__ float sigm_n(float x) { return rcpf(1.0f + __expf(-x)); }
__device__ __forceinline__ float tanh_n(float x) {
    float ax = fabsf(x);
    float e = __expf(-2.0f * ax);
    float t = (1.0f - e) * rcpf(1.0f + e);
    return copysignf(t, x);
}
__device__ __forceinline__ float tanh_s(float x) { return tanh_n(x); }

// ---------------- kernel 0: prep ----------------
// wih_t: (K=128, 512) for gemm1. bias = b_ih + b_hh.
// whh_pk: packed for lstm_seq pk_fma; dest idx bit fields:
//   [1:0]=j4, [3:2]=q, [10:4]=d, [12:11]=gi, [15:13]=kk4
//   source k = q*32 + kk4*4 + j4, source row j = gi*128 + d  (w_hh is (4H,H))
__global__ __launch_bounds__(256) void prep_kernel(
    const float* __restrict__ w_ih, const float* __restrict__ b_ih,
    const float* __restrict__ w_hh, const float* __restrict__ b_hh,
    float* __restrict__ wih_t, float* __restrict__ whh_pk, float* __restrict__ bias) {
    int idx = blockIdx.x * blockDim.x + threadIdx.x;   // 0..65535
    if (idx < G4H * Isz) {
        int j = idx >> 7;
        int k = idx & 127;
        wih_t[k * G4H + j] = w_ih[idx];

        int j4  = idx & 3;
        int q   = (idx >> 2) & 3;
        int d   = (idx >> 4) & 127;
        int gi  = (idx >> 11) & 3;
        int kk4 = (idx >> 13) & 7;
        whh_pk[idx] = w_hh[(size_t)((gi << 7) + d) * 128 + (q << 5) + (kk4 << 2) + j4];
    }
    if (idx < G4H) bias[idx] = b_ih[idx] + b_hh[idx];
}

// ---------------- gemm128: C[M,N] = A[M,K] @ B[K,N] (+bias[N]) ----------------
#define GBK 16
#define GLD 132

__global__ __launch_bounds__(256) void gemm128(
    const float* __restrict__ A, const float* __restrict__ Bm,
    const float* __restrict__ bias, float* __restrict__ C,
    int M, int N, int K) {
    __shared__ float As[GBK][GLD];
    __shared__ float Bs[GBK][GLD];
    const int tid = threadIdx.x;
    const int bm = blockIdx.y * 128;
    const int bn = blockIdx.x * 128;
    const int tx = tid & 15, ty = tid >> 4;
    float acc[8][8] = {};

    const int ar = tid >> 2;
    const int ac = (tid & 3) * 4;
    const int br = tid >> 5;
    const int bc = (tid & 31) * 4;

    for (int k0 = 0; k0 < K; k0 += GBK) {
        #pragma unroll
        for (int h = 0; h < 2; ++h) {
            int r = ar + 64 * h;
            float4 v = *(const float4*)(A + (size_t)(bm + r) * K + k0 + ac);
            As[ac + 0][r] = v.x;
            As[ac + 1][r] = v.y;
            As[ac + 2][r] = v.z;
            As[ac + 3][r] = v.w;
        }
        #pragma unroll
        for (int h = 0; h < 2; ++h) {
            int kr = br + 8 * h;
            float4 v = *(const float4*)(Bm + (size_t)(k0 + kr) * N + bn + bc);
            *(float4*)&Bs[kr][bc] = v;
        }
        __syncthreads();
        #pragma unroll
        for (int kk = 0; kk < GBK; ++kk) {
            float a[8], b[8];
            *(float4*)&a[0] = *(const float4*)&As[kk][ty * 8];
            *(float4*)&a[4] = *(const float4*)&As[kk][ty * 8 + 4];
            *(float4*)&b[0] = *(const float4*)&Bs[kk][tx * 8];
            *(float4*)&b[4] = *(const float4*)&Bs[kk][tx * 8 + 4];
            #pragma unroll
            for (int i = 0; i < 8; ++i)
                #pragma unroll
                for (int j = 0; j < 8; ++j)
                    acc[i][j] = fmaf(a[i], b[j], acc[i][j]);
        }
        __syncthreads();
    }
    float bb[8];
    #pragma unroll
    for (int j = 0; j < 8; ++j) bb[j] = bias ? bias[bn + tx * 8 + j] : 0.0f;
    #pragma unroll
    for (int i = 0; i < 8; ++i) {
        int row = bm + ty * 8 + i;
        float4 v0, v1;
        v0.x = acc[i][0] + bb[0]; v0.y = acc[i][1] + bb[1];
        v0.z = acc[i][2] + bb[2]; v0.w = acc[i][3] + bb[3];
        v1.x = acc[i][4] + bb[4]; v1.y = acc[i][5] + bb[5];
        v1.z = acc[i][6] + bb[6]; v1.w = acc[i][7] + bb[7];
        *(float4*)(C + (size_t)row * N + bn + tx * 8) = v0;
        *(float4*)(C + (size_t)row * N + bn + tx * 8 + 4) = v1;
    }
}

// ---------------- kernel 2: sequential LSTM recurrence, one WG per batch ----------------
// R3 structure (512 thr, (d,q) layout, weights in 128 VGPRs, one barrier/step)
// + batched global IO: G loaded 8 steps at a time into registers (loads first,
// so vmcnt waits for gb[s] don't force store completion), h stored via an
// 8-deep VGPR ring flushed once per chunk. 7 of 8 barriers drain nothing;
// the 8th drains ops issued ~1 step earlier (mostly complete).
#define HPAD(k) ((k) + 8 * ((k) >> 5))

__global__ __launch_bounds__(512, 2) void lstm_seq(
    const float* __restrict__ G, const float* __restrict__ whh_pk,
    float* __restrict__ H_all) {
    const int b = blockIdx.x;
    const int tid = threadIdx.x;
    const int d = tid >> 2;
    const int q = tid & 3;

    __shared__ float h_s[2][160];

    // one-time coalesced weight load
    float2 w2v[4][16];
    {
        const float4* wp = (const float4*)whh_pk;
        #pragma unroll
        for (int kk4 = 0; kk4 < 8; ++kk4)
            #pragma unroll
            for (int gi = 0; gi < 4; ++gi) {
                float4 v = wp[((kk4 * 4 + gi) * 128 + d) * 4 + q];
                w2v[gi][kk4 * 2]     = make_float2(v.x, v.y);
                w2v[gi][kk4 * 2 + 1] = make_float2(v.z, v.w);
            }
    }

    if (tid < 320) ((float*)h_s)[tid] = 0.0f;
    float c = 0.0f;
    __syncthreads();

    const float* Gq = G + (size_t)b * Tsz * G4H + q * 128 + d;
    float* Hst = H_all + (size_t)b * Tsz * Hsz + d;   // q==0 lanes store

    float hring[8];
    int cur = 0;

    for (int t0 = 0; t0 < Tsz; t0 += 8) {
        // batched G loads for this chunk (issued FIRST: oldest in vmcnt order)
        float gb[8];
        #pragma unroll
        for (int s = 0; s < 8; ++s) gb[s] = Gq[(size_t)(t0 + s) * G4H];
        // flush previous chunk's h ring (stores issued after loads)
        if (t0 > 0 && q == 0) {
            #pragma unroll
            for (int s = 0; s < 8; ++s) Hst[(size_t)(t0 - 8 + s) * Hsz] = hring[s];
        }

        #pragma unroll
        for (int ph = 0; ph < 8; ++ph) {
            float gval = gb[ph];
            float2 accA[4], accB[4];
            #pragma unroll
            for (int gi = 0; gi < 4; ++gi) {
                accA[gi] = make_float2(q == gi ? gval : 0.f, 0.f);
                accB[gi] = make_float2(0.f, 0.f);
            }
            const float4* hb4 = (const float4*)&h_s[cur][q * 40];  // HPAD(q*32)=q*40
            #pragma unroll
            for (int kk4 = 0; kk4 < 8; ++kk4) {
                float4 h4 = hb4[kk4];
                float2 hA = make_float2(h4.x, h4.y);
                float2 hB = make_float2(h4.z, h4.w);
                accA[0] = pk_fma(hA, w2v[0][2 * kk4], accA[0]);
                accA[1] = pk_fma(hA, w2v[1][2 * kk4], accA[1]);
                accA[2] = pk_fma(hA, w2v[2][2 * kk4], accA[2]);
                accA[3] = pk_fma(hA, w2v[3][2 * kk4], accA[3]);
                accB[0] = pk_fma(hB, w2v[0][2 * kk4 + 1], accB[0]);
                accB[1] = pk_fma(hB, w2v[1][2 * kk4 + 1], accB[1]);
                accB[2] = pk_fma(hB, w2v[2][2 * kk4 + 1], accB[2]);
                accB[3] = pk_fma(hB, w2v[3][2 * kk4 + 1], accB[3]);
            }
            float a0 = quad_rsum(accA[0].x + accA[0].y + accB[0].x + accB[0].y);
            float a1 = quad_rsum(accA[1].x + accA[1].y + accB[1].x + accB[1].y);
            float a2 = quad_rsum(accA[2].x + accA[2].y + accB[2].x + accB[2].y);
            float a3 = quad_rsum(accA[3].x + accA[3].y + accB[3].x + accB[3].y);

            float iv = sigm_n(a0);
            float fv = sigm_n(a1);
            float gv = tanh_n(a2);
            float ov = sigm_n(a3);
            c = fv * c + iv * gv;
            float h = ov * tanh_n(c);

            if (q == 0) h_s[cur ^ 1][HPAD(d)] = h;
            hring[ph] = h;          // uniform write (only q==0's copy is stored)
            __syncthreads();
            cur ^= 1;
        }
    }
    // final flush: steps 248..255
    if (q == 0) {
        #pragma unroll
        for (int s = 0; s < 8; ++s) Hst[(size_t)(248 + s) * Hsz] = hring[s];
    }
}

// ---------------- kernel 3: final attention + FC, one WG per batch ----------------
__global__ __launch_bounds__(256) void attn_out(
    const float* __restrict__ H_all, const float* __restrict__ KV,
    const float* __restrict__ w1, const float* __restrict__ w2,
    const float* __restrict__ w_fc, const float* __restrict__ b_fc,
    float* __restrict__ out) {
    int b = blockIdx.x;
    int tid = threadIdx.x;
    __shared__ float hT[Hsz];
    __shared__ float q_s[Hsz];
    __shared__ float w2s[Hsz];
    __shared__ float s_s[Tsz];
    __shared__ float r2[2][Hsz];
    __shared__ float r_s[Hsz];

    const float* Hb = H_all + (size_t)b * Tsz * Hsz;
    const float* KVb = KV + (size_t)b * Tsz * Hsz;

    if (tid < Hsz) {
        hT[tid] = Hb[255 * Hsz + tid];
        w2s[tid] = w2[tid];
    }
    __syncthreads();
    if (tid < Hsz) {
        float acc = 0.f;
        #pragma unroll 8
        for (int k = 0; k < Hsz; ++k) acc = fmaf(hT[k], w1[k * Hsz + tid], acc);
        q_s[tid] = acc;
    }
    __syncthreads();

    const int qd = tid >> 2, ql = tid & 3;
    #pragma unroll
    for (int jj = 0; jj < 4; ++jj) {
        int j = qd + jj * 64;
        float p = 0.f;
        if (j < 255) {
            const float* kv = KVb + (size_t)j * Hsz + ql * 32;
            const float* qs = q_s + ql * 32;
            const float* wv = w2s + ql * 32;
            #pragma unroll 8
            for (int k = 0; k < 32; ++k)
                p = fmaf(tanh_s(qs[k] + kv[k]), wv[k], p);
        }
        p = quad_rsum(p);
        if (ql == 0 && j < 255) s_s[j] = p;
    }
    __syncthreads();

    {
        int dd = tid & 127, half = tid >> 7;
        int j0 = half * 128, je = half ? 255 : 128;
        float acc = 0.f;
        #pragma unroll 4
        for (int j = j0; j < je; ++j) acc = fmaf(s_s[j], Hb[(size_t)j * Hsz + dd], acc);
        r2[half][dd] = acc;
    }
    __syncthreads();
    if (tid < Hsz) r_s[tid] = hT[tid] + r2[0][tid] + r2[1][tid];
    __syncthreads();

    {
        int o = tid >> 1, half = tid & 1;
        float acc = 0.f;
        if (o < Csz) {
            const float* wr = w_fc + (size_t)o * Hsz + half * 64;
            const float* rr = r_s + half * 64;
            #pragma unroll 8
            for (int k = 0; k < 64; ++k) acc = fmaf(rr[k], wr[k], acc);
        }
        acc += __shfl_xor(acc, 1);
        if (half == 0 && o < Csz) out[b * Csz + o] = acc + b_fc[o];
    }
}

// ---------------- launch ----------------
extern "C" void kernel_launch(void* const* d_in, const int* in_sizes, int n_in,
                              void* d_out, int out_size, void* d_ws, size_t ws_size,
                              hipStream_t stream) {
    const float* x    = (const float*)d_in[0];
    const float* w_ih = (const float*)d_in[1];
    const float* b_ih = (const float*)d_in[2];
    const float* w_hh = (const float*)d_in[3];
    const float* b_hh = (const float*)d_in[4];
    const float* w1   = (const float*)d_in[5];
    const float* w2   = (const float*)d_in[6];
    const float* w_fc = (const float*)d_in[7];
    const float* b_fc = (const float*)d_in[8];

    float* ws = (float*)d_ws;
    float* wih_t  = ws;                      // 128*512
    float* whh_pk = wih_t + 65536;           // 128*512 (packed lstm layout)
    float* bias   = whh_pk + 65536;          // 512
    float* G      = bias + 512;              // 8192*512
    float* H_all  = G + 4194304;             // 32*256*128
    float* KV     = H_all + 1048576;         // 32*256*128

    prep_kernel<<<256, 256, 0, stream>>>(w_ih, b_ih, w_hh, b_hh, wih_t, whh_pk, bias);

    dim3 g1(G4H / 128, (Bsz * Tsz) / 128);   // (4, 64)
    gemm128<<<g1, 256, 0, stream>>>(x, wih_t, bias, G, Bsz * Tsz, G4H, Isz);

    lstm_seq<<<Bsz, 512, 0, stream>>>(G, whh_pk, H_all);

    dim3 g2(Hsz / 128, (Bsz * Tsz) / 128);   // (1, 64)
    gemm128<<<g2, 256, 0, stream>>>(H_all, w1 + Hsz * Hsz, nullptr, KV, Bsz * Tsz, Hsz, Hsz);

    attn_out<<<Bsz, 256, 0, stream>>>(H_all, KV, w1, w2, w_fc, b_fc, (float*)d_out);
}